// Round 3
// baseline (624.729 us; speedup 1.0000x reference)
//
#include <hip/hip_runtime.h>
#include <cstdint>

#define NNUM 100
#define NCAT 100
#define CATC 100
#define NCOND 128
#define GN_EPS 1e-5f

typedef __attribute__((ext_vector_type(8))) short bfrag8;   // 8 bf16 = 4 VGPRs
typedef __attribute__((ext_vector_type(4))) float accf4;    // 4 fp32 acc

__device__ __forceinline__ float sigmoidf_(float x) { return 1.0f / (1.0f + __expf(-x)); }

__device__ __forceinline__ ushort f2bf(float f) {
    uint32_t u = __builtin_bit_cast(uint32_t, f);
    u += 0x7fffu + ((u >> 16) & 1u);   // round-to-nearest-even
    return (ushort)(u >> 16);
}
__device__ __forceinline__ float bf2f(ushort h) {
    return __builtin_bit_cast(float, (uint32_t)h << 16);
}

// ---------------------------------------------------------------------------
// One-time prep: W_cat fp32 [g][k][c] -> split-bf16 hi/lo planes laid out in
// MFMA B-fragment order, so the GEMM loads fragments directly with 16B
// global loads (L2-resident; 32 b-blocks share each g slice).
// Layout (ushort): Wf[g*32768 + ((t*4 + kk)*2 + plane)*512 + lane*8 + j]
//   where fragment (t,kk): c = t*16 + (lane&15), k = kk*32 + (lane>>4)*8 + j.
// ---------------------------------------------------------------------------
__global__ __launch_bounds__(256)
void prep_wcat(const float* __restrict__ W_cat, ushort* __restrict__ Wf)
{
    const int g    = blockIdx.x;
    const int lane = threadIdx.x & 63;
    const int w    = threadIdx.x >> 6;
    const float* Wg = W_cat + ((size_t)g << 14);
    ushort* Wfg = Wf + ((size_t)g << 15);
    #pragma unroll
    for (int i = 0; i < 8; ++i) {
        int p  = w * 8 + i;           // 0..31 (t,kk) pairs
        int t  = p >> 2, kk = p & 3;
        int c  = t * 16 + (lane & 15);
        int kb = kk * 32 + ((lane >> 4) << 3);
        ushort hi[8], lo[8];
        #pragma unroll
        for (int j = 0; j < 8; ++j) {
            float v = Wg[(kb + j) * NCOND + c];
            ushort h = f2bf(v);
            hi[j] = h;
            lo[j] = f2bf(v - bf2f(h));
        }
        int off = ((t * 4 + kk) * 2) * 512 + lane * 8;
        *(bfrag8*)(Wfg + off)       = *(const bfrag8*)hi;
        *(bfrag8*)(Wfg + off + 512) = *(const bfrag8*)lo;
    }
}

// ---------------------------------------------------------------------------
// Pass 1: per-column (g) GEMM, split-bf16 (hi/lo) 3-term MFMA.
//   z = A_hi@W_hi + A_hi@W_lo + A_lo@W_hi
// WAVE-LOCAL staging: wave w stages rows 32w..32w+31 into its own LDS region
// and computes m-groups {2w, 2w+1} (exactly those rows) -> no __syncthreads,
// just a same-wave s_waitcnt lgkmcnt(0). x_cat indices prefetched in one
// gather and broadcast via __shfl so emb row loads pipeline (MLP).
// [m][k] LDS with XOR swizzle (m&7)<<4; W fragments straight from Wf.
// LDS = 64 KB -> 2 blocks/CU.
// ---------------------------------------------------------------------------
template<int DIRECT>
__global__ __launch_bounds__(256, 2)
void cat_gemm_kernel(const int* __restrict__ x_cat,
                     const float* __restrict__ emb_table,
                     const float* __restrict__ gn_w,
                     const float* __restrict__ gn_b,
                     const ushort* __restrict__ Wf,
                     const float* __restrict__ b_cat,
                     float* __restrict__ dst)
{
    const int g    = blockIdx.y;
    const int b0   = blockIdx.x * 128;
    const int tid  = threadIdx.x;
    const int lane = tid & 63;
    const int w    = tid >> 6;    // wave 0..3

    __shared__ __align__(16) ushort Ahi[128 * 128];   // [m][k] swizzled, 32 KB
    __shared__ __align__(16) ushort Alo[128 * 128];   // 32 KB

    const int half = lane >> 5;       // which row of the pair
    const int l5   = lane & 31;       // owns k = 4*l5 .. 4*l5+3
    float4 gwv = *(const float4*)(gn_w + g * NCOND + l5 * 4);
    float4 gbv = *(const float4*)(gn_b + g * NCOND + l5 * 4);

    // prefetch: lane (l&31) holds idx for this wave's row (l&31)
    int myidx = x_cat[(size_t)(b0 + w * 32 + (lane & 31)) * NCAT + g];

    #pragma unroll 8
    for (int it = 0; it < 16; ++it) {
        int r = it * 2 + half;            // row within wave's 32
        int m = w * 32 + r;
        int idx = __shfl(myidx, r, 64);
        const float4* row = (const float4*)(emb_table + ((size_t)(g * CATC + idx) << 7));
        float4 v = row[l5];
        float s  = v.x + v.y + v.z + v.w;
        float ss = v.x * v.x + v.y * v.y + v.z * v.z + v.w * v.w;
        #pragma unroll
        for (int off = 16; off > 0; off >>= 1) {   // stays within 32-lane half
            s  += __shfl_xor(s,  off, 64);
            ss += __shfl_xor(ss, off, 64);
        }
        float mean = s * 0.0078125f;
        float var  = fmaf(-mean, mean, ss * 0.0078125f);
        float rs   = rsqrtf(var + GN_EPS);
        float n0 = fmaf((v.x - mean) * rs, gwv.x, gbv.x);
        float n1 = fmaf((v.y - mean) * rs, gwv.y, gbv.y);
        float n2 = fmaf((v.z - mean) * rs, gwv.z, gbv.z);
        float n3 = fmaf((v.w - mean) * rs, gwv.w, gbv.w);
        ushort h0 = f2bf(n0), h1 = f2bf(n1), h2 = f2bf(n2), h3 = f2bf(n3);
        uint2 hp = { (uint32_t)h0 | ((uint32_t)h1 << 16),
                     (uint32_t)h2 | ((uint32_t)h3 << 16) };
        uint2 lp = { (uint32_t)f2bf(n0 - bf2f(h0)) | ((uint32_t)f2bf(n1 - bf2f(h1)) << 16),
                     (uint32_t)f2bf(n2 - bf2f(h2)) | ((uint32_t)f2bf(n3 - bf2f(h3)) << 16) };
        int bo = m * 256 + ((l5 * 8) ^ ((m & 7) << 4));   // swizzled byte offset
        *(uint2*)((char*)Ahi + bo) = hp;
        *(uint2*)((char*)Alo + bo) = lp;
    }
    // wave-local producer->consumer: all ds_writes are this wave's own region
    asm volatile("s_waitcnt lgkmcnt(0)" ::: "memory");

    accf4 acc[2][8];
    #pragma unroll
    for (int gi = 0; gi < 2; ++gi)
        #pragma unroll
        for (int t = 0; t < 8; ++t)
            acc[gi][t] = (accf4){0.f, 0.f, 0.f, 0.f};

    const ushort* Wfg = Wf + ((size_t)g << 15);
    const int row0 = w * 32 + (lane & 15);          // group 2w
    const int sw   = (lane & 7) << 4;               // (row&7)<<4; rows differ by 16 -> same

    #pragma unroll
    for (int kk = 0; kk < 4; ++kk) {
        int colb = kk * 64 + ((lane >> 4) << 4);    // pre-swizzle byte col
        int o0 = row0 * 256 + (colb ^ sw);
        int o1 = o0 + 16 * 256;                      // group 2w+1
        bfrag8 ah0 = *(const bfrag8*)((const char*)Ahi + o0);
        bfrag8 al0 = *(const bfrag8*)((const char*)Alo + o0);
        bfrag8 ah1 = *(const bfrag8*)((const char*)Ahi + o1);
        bfrag8 al1 = *(const bfrag8*)((const char*)Alo + o1);
        const ushort* wbase = Wfg + kk * 1024 + lane * 8;
        #pragma unroll
        for (int t = 0; t < 8; ++t) {
            bfrag8 wh = *(const bfrag8*)(wbase + t * 4096);
            bfrag8 wl = *(const bfrag8*)(wbase + t * 4096 + 512);
            acc[0][t] = __builtin_amdgcn_mfma_f32_16x16x32_bf16(ah0, wh, acc[0][t], 0, 0, 0);
            acc[0][t] = __builtin_amdgcn_mfma_f32_16x16x32_bf16(ah0, wl, acc[0][t], 0, 0, 0);
            acc[0][t] = __builtin_amdgcn_mfma_f32_16x16x32_bf16(al0, wh, acc[0][t], 0, 0, 0);
            acc[1][t] = __builtin_amdgcn_mfma_f32_16x16x32_bf16(ah1, wh, acc[1][t], 0, 0, 0);
            acc[1][t] = __builtin_amdgcn_mfma_f32_16x16x32_bf16(ah1, wl, acc[1][t], 0, 0, 0);
            acc[1][t] = __builtin_amdgcn_mfma_f32_16x16x32_bf16(al1, wh, acc[1][t], 0, 0, 0);
        }
    }

    // ---- epilogue: + b_cat, sigmoid, store ----
    const float* bcg = b_cat + g * NCOND;
    const int colL = lane & 15;
    const int quad = lane >> 4;
    #pragma unroll
    for (int t = 0; t < 8; ++t) {
        int c = t * 16 + colL;
        float bc = bcg[c];
        #pragma unroll
        for (int gi = 0; gi < 2; ++gi) {
            int mbase = (2 * w + gi) * 16 + quad * 4;
            #pragma unroll
            for (int r = 0; r < 4; ++r) {
                int b = b0 + mbase + r;
                float v = sigmoidf_(acc[gi][t][r] + bc);
                if (DIRECT) {
                    dst[(size_t)b * (128 * 200) + (size_t)c * 200 + 100 + g] = v;
                } else {
                    dst[(size_t)b * (NCAT * NCOND) + g * NCOND + c] = v;
                }
            }
        }
    }
}

// ---------------------------------------------------------------------------
// Transpose W_num/b_num (100x128 -> 128x100) into ws for coalesced pass-2 reads
// ---------------------------------------------------------------------------
__global__ __launch_bounds__(256)
void transpose_wn(const float* __restrict__ W_num, const float* __restrict__ b_num,
                  float* __restrict__ Wt, float* __restrict__ Bt)
{
    int idx = blockIdx.x * 256 + threadIdx.x;
    if (idx < NCOND * NNUM) {
        int c = idx / NNUM, j = idx - c * NNUM;
        Wt[idx] = W_num[j * NCOND + c];
        Bt[idx] = b_num[j * NCOND + c];
    }
}

// ---------------------------------------------------------------------------
// Pass 2: per-(sample, c-half). LDS-transpose a (100 x 64) cat slice, fuse
// num branch, write the contiguous float4 range out[b, h*64..h*64+64, :].
// LDS 26.4 KB -> 6 blocks/CU (75% occupancy). All global IO float4-coalesced.
// ---------------------------------------------------------------------------
__global__ __launch_bounds__(256)
void finalize_kernel(const float* __restrict__ ws_cat,
                     const float* __restrict__ Wt,   // [c][j]
                     const float* __restrict__ Bt,   // [c][j]
                     const float* __restrict__ x_num,
                     float* __restrict__ out)
{
    const int b   = blockIdx.x;
    const int h   = blockIdx.y;       // c-half: 0 or 1
    const int tid = threadIdx.x;
    __shared__ float T[NCAT * 65];    // [g][c_loc], pad 65
    __shared__ float xr[NNUM];

    if (tid < NNUM) xr[tid] = x_num[b * NNUM + tid];

    const float4* src = (const float4*)(ws_cat + (size_t)b * (NCAT * NCOND));
    #pragma unroll
    for (int it = 0; it < 7; ++it) {
        int i4 = it * 256 + tid;                  // 0..1599 float4s of this half
        if (i4 < NCAT * 16) {
            int gg  = i4 >> 4;                    // g
            int cc4 = i4 & 15;                    // float4 within half
            float4 v = src[gg * 32 + h * 16 + cc4];
            float* d = &T[gg * 65 + cc4 * 4];
            d[0] = v.x; d[1] = v.y; d[2] = v.z; d[3] = v.w;
        }
    }
    __syncthreads();

    float4* outb = (float4*)(out + (size_t)b * (NCOND * 200)) + h * 3200;
    const float4* Wt4 = (const float4*)Wt;
    const float4* Bt4 = (const float4*)Bt;
    #pragma unroll
    for (int it = 0; it < 13; ++it) {
        int o4 = it * 256 + tid;                  // 0..3199 float4s of this half
        if (o4 < 64 * 50) {
            int c_loc = o4 / 50;
            int j4    = o4 - c_loc * 50;
            int c     = h * 64 + c_loc;
            float4 v;
            if (j4 < 25) {
                float4 wv = Wt4[c * 25 + j4];
                float4 bv = Bt4[c * 25 + j4];
                int j = j4 * 4;
                v.x = sigmoidf_(fmaf(xr[j],     wv.x, bv.x));
                v.y = sigmoidf_(fmaf(xr[j + 1], wv.y, bv.y));
                v.z = sigmoidf_(fmaf(xr[j + 2], wv.z, bv.z));
                v.w = sigmoidf_(fmaf(xr[j + 3], wv.w, bv.w));
            } else {
                int gg = (j4 - 25) * 4;
                v.x = T[(gg    ) * 65 + c_loc];
                v.y = T[(gg + 1) * 65 + c_loc];
                v.z = T[(gg + 2) * 65 + c_loc];
                v.w = T[(gg + 3) * 65 + c_loc];
            }
            outb[o4] = v;
        }
    }
}

// ---------------------------------------------------------------------------
// Fallback num-branch kernel (only used if ws too small for two-pass)
// ---------------------------------------------------------------------------
__global__ __launch_bounds__(256)
void num_direct(const float* __restrict__ x_num, const float* __restrict__ W_num,
                const float* __restrict__ b_num, float* __restrict__ out, int B)
{
    size_t i = (size_t)blockIdx.x * 256 + threadIdx.x;
    size_t total = (size_t)B * NCOND * NNUM;
    if (i >= total) return;
    int n = (int)(i % NNUM);
    size_t t = i / NNUM;
    int c = (int)(t % NCOND);
    int b = (int)(t / NCOND);
    float v = sigmoidf_(x_num[b * NNUM + n] * W_num[n * NCOND + c] + b_num[n * NCOND + c]);
    out[(size_t)b * (NCOND * 200) + (size_t)c * 200 + n] = v;
}

extern "C" void kernel_launch(void* const* d_in, const int* in_sizes, int n_in,
                              void* d_out, int out_size, void* d_ws, size_t ws_size,
                              hipStream_t stream)
{
    const float* x_num  = (const float*)d_in[0];
    const int*   x_cat  = (const int*)  d_in[1];
    const float* W_num  = (const float*)d_in[2];
    const float* b_num  = (const float*)d_in[3];
    const float* emb    = (const float*)d_in[4];
    const float* gn_w   = (const float*)d_in[5];
    const float* gn_b   = (const float*)d_in[6];
    const float* W_cat  = (const float*)d_in[7];
    const float* b_cat  = (const float*)d_in[8];
    float* out = (float*)d_out;

    const int B = in_sizes[0] / NNUM;                 // 4096
    const size_t cat_bytes = (size_t)B * NCAT * NCOND * sizeof(float);
    const size_t wtbt     = 2 * (size_t)NCOND * NNUM * sizeof(float);
    const size_t wf_bytes = (size_t)NCAT * 32768 * sizeof(ushort);   // 6.55 MB
    const size_t need  = cat_bytes + wtbt;
    const size_t need2 = need + wf_bytes;

    dim3 gemm_grid(B / 128, NCAT);

    if (ws_size >= need) {
        float* ws_cat = (float*)d_ws;
        float* Wt = (float*)((char*)d_ws + cat_bytes);
        float* Bt = Wt + NCOND * NNUM;
        // Wf in ws if it fits, else in the output buffer as scratch
        // (finalize overwrites every byte of out afterwards).
        ushort* Wf = (ws_size >= need2) ? (ushort*)((char*)d_ws + need)
                                        : (ushort*)out;
        prep_wcat<<<NCAT, 256, 0, stream>>>(W_cat, Wf);
        transpose_wn<<<(NCOND * NNUM + 255) / 256, 256, 0, stream>>>(W_num, b_num, Wt, Bt);
        cat_gemm_kernel<0><<<gemm_grid, 256, 0, stream>>>(x_cat, emb, gn_w, gn_b, Wf, b_cat, ws_cat);
        finalize_kernel<<<dim3(B, 2), 256, 0, stream>>>(ws_cat, Wt, Bt, x_num, out);
    } else {
        // fallback: Wf in ws (6.55 MB), direct strided writes to out
        ushort* Wf = (ushort*)d_ws;
        prep_wcat<<<NCAT, 256, 0, stream>>>(W_cat, Wf);
        cat_gemm_kernel<1><<<gemm_grid, 256, 0, stream>>>(x_cat, emb, gn_w, gn_b, Wf, b_cat, out);
        size_t total = (size_t)B * NCOND * NNUM;
        num_direct<<<(total + 255) / 256, 256, 0, stream>>>(x_num, W_num, b_num, out, B);
    }
}

// Round 4
// 513.427 us; speedup vs baseline: 1.2168x; 1.2168x over previous
//
#include <hip/hip_runtime.h>
#include <cstdint>

#define NNUM 100
#define NCAT 100
#define CATC 100
#define NCOND 128
#define GN_EPS 1e-5f

typedef __attribute__((ext_vector_type(8))) short bfrag8;   // 8 bf16 = 4 VGPRs
typedef __attribute__((ext_vector_type(4))) float accf4;    // 4 fp32 acc

__device__ __forceinline__ float sigmoidf_(float x) { return 1.0f / (1.0f + __expf(-x)); }

__device__ __forceinline__ ushort f2bf(float f) {
    uint32_t u = __builtin_bit_cast(uint32_t, f);
    u += 0x7fffu + ((u >> 16) & 1u);   // round-to-nearest-even
    return (ushort)(u >> 16);
}
__device__ __forceinline__ float bf2f(ushort h) {
    return __builtin_bit_cast(float, (uint32_t)h << 16);
}

// ---------------------------------------------------------------------------
// prep_wcat: W' = diag(gn_w) * W_cat  ->  split-bf16 hi/lo planes in MFMA
// B-fragment order (same layout as previous rounds, now gn_w-scaled).
// Wf[g*32768 + ((t*4+kk)*2 + plane)*512 + lane*8 + j]
//   fragment (t,kk): c = t*16 + (lane&15), k = kk*32 + (lane>>4)*8 + j.
// ---------------------------------------------------------------------------
__global__ __launch_bounds__(256)
void prep_wcat(const float* __restrict__ W_cat, const float* __restrict__ gn_w,
               ushort* __restrict__ Wf)
{
    const int g    = blockIdx.x;
    const int lane = threadIdx.x & 63;
    const int w    = threadIdx.x >> 6;
    const float* Wg = W_cat + ((size_t)g << 14);
    const float* gwg = gn_w + g * NCOND;
    ushort* Wfg = Wf + ((size_t)g << 15);
    #pragma unroll
    for (int i = 0; i < 8; ++i) {
        int p  = w * 8 + i;           // 0..31 (t,kk) pairs
        int t  = p >> 2, kk = p & 3;
        int c  = t * 16 + (lane & 15);
        int kb = kk * 32 + ((lane >> 4) << 3);
        ushort hi[8], lo[8];
        #pragma unroll
        for (int j = 0; j < 8; ++j) {
            float v = gwg[kb + j] * Wg[(kb + j) * NCOND + c];
            ushort h = f2bf(v);
            hi[j] = h;
            lo[j] = f2bf(v - bf2f(h));
        }
        int off = ((t * 4 + kk) * 2) * 512 + lane * 8;
        *(bfrag8*)(Wfg + off)       = *(const bfrag8*)hi;
        *(bfrag8*)(Wfg + off + 512) = *(const bfrag8*)lo;
    }
}

// ---------------------------------------------------------------------------
// prep_stats: per emb-table row (10,000 rows), S[r] = (rs, -mean*rs).
// One row per wave, float2/lane, 6-stage butterfly.
// ---------------------------------------------------------------------------
__global__ __launch_bounds__(256)
void prep_stats(const float* __restrict__ emb_table, float2* __restrict__ S)
{
    int r = blockIdx.x * 4 + (threadIdx.x >> 6);
    int lane = threadIdx.x & 63;
    if (r >= NCAT * CATC) return;
    const float2* row = (const float2*)(emb_table + ((size_t)r << 7));
    float2 v = row[lane];
    float s  = v.x + v.y;
    float ss = v.x * v.x + v.y * v.y;
    #pragma unroll
    for (int off = 32; off > 0; off >>= 1) {
        s  += __shfl_xor(s,  off, 64);
        ss += __shfl_xor(ss, off, 64);
    }
    float mean = s * 0.0078125f;
    float var  = fmaf(-mean, mean, ss * 0.0078125f);
    float rs   = rsqrtf(var + GN_EPS);
    if (lane == 0) S[r] = make_float2(rs, -mean * rs);
}

// ---------------------------------------------------------------------------
// prep_qp: Q[g][o] = sum_i gn_w[g,i]*W[g,i,o];  P[g][o] = sum_i gn_b[g,i]*W + b_cat.
// Block per g, 128 threads (one per o); W row reads fully coalesced.
// ---------------------------------------------------------------------------
__global__ __launch_bounds__(128)
void prep_qp(const float* __restrict__ W_cat, const float* __restrict__ gn_w,
             const float* __restrict__ gn_b, const float* __restrict__ b_cat,
             float* __restrict__ Q, float* __restrict__ P)
{
    const int g = blockIdx.x, o = threadIdx.x;
    const float* Wg = W_cat + ((size_t)g << 14);
    float q = 0.f, p = 0.f;
    #pragma unroll 4
    for (int i = 0; i < NCOND; ++i) {
        float wv = Wg[i * NCOND + o];
        q = fmaf(gn_w[g * NCOND + i], wv, q);
        p = fmaf(gn_b[g * NCOND + i], wv, p);
    }
    Q[g * NCOND + o] = q;
    P[g * NCOND + o] = p + b_cat[g * NCOND + o];
}

// ---------------------------------------------------------------------------
// prep_E: E[g][cat][o] = emb_row(g,cat) @ W'(g)  for all 100 cats per g.
// One block per g. A = raw emb rows (rows >=100 duplicate row 99, discarded).
// FULL 4-term split-bf16 (hh + hl + lh + ll) -> ~fp32 accuracy.
// Wave-local staging (no barrier), XOR-swizzled [m][k] LDS as before.
// ---------------------------------------------------------------------------
__global__ __launch_bounds__(256, 2)
void prep_E_kernel(const float* __restrict__ emb_table,
                   const ushort* __restrict__ Wf,
                   float* __restrict__ E)
{
    const int g    = blockIdx.x;
    const int tid  = threadIdx.x;
    const int lane = tid & 63;
    const int w    = tid >> 6;

    __shared__ __align__(16) ushort Ahi[128 * 128];
    __shared__ __align__(16) ushort Alo[128 * 128];

    const int half = lane >> 5;
    const int l5   = lane & 31;

    #pragma unroll 8
    for (int it = 0; it < 16; ++it) {
        int r = it * 2 + half;
        int m = w * 32 + r;
        int row_id = m < CATC ? m : (CATC - 1);
        const float4* row = (const float4*)(emb_table + ((size_t)(g * CATC + row_id) << 7));
        float4 v = row[l5];
        ushort h0 = f2bf(v.x), h1 = f2bf(v.y), h2 = f2bf(v.z), h3 = f2bf(v.w);
        uint2 hp = { (uint32_t)h0 | ((uint32_t)h1 << 16),
                     (uint32_t)h2 | ((uint32_t)h3 << 16) };
        uint2 lp = { (uint32_t)f2bf(v.x - bf2f(h0)) | ((uint32_t)f2bf(v.y - bf2f(h1)) << 16),
                     (uint32_t)f2bf(v.z - bf2f(h2)) | ((uint32_t)f2bf(v.w - bf2f(h3)) << 16) };
        int bo = m * 256 + ((l5 * 8) ^ ((m & 7) << 4));
        *(uint2*)((char*)Ahi + bo) = hp;
        *(uint2*)((char*)Alo + bo) = lp;
    }
    asm volatile("s_waitcnt lgkmcnt(0)" ::: "memory");

    accf4 acc[2][8];
    #pragma unroll
    for (int gi = 0; gi < 2; ++gi)
        #pragma unroll
        for (int t = 0; t < 8; ++t)
            acc[gi][t] = (accf4){0.f, 0.f, 0.f, 0.f};

    const ushort* Wfg = Wf + ((size_t)g << 15);
    const int row0 = w * 32 + (lane & 15);
    const int sw   = (lane & 7) << 4;

    #pragma unroll
    for (int kk = 0; kk < 4; ++kk) {
        int colb = kk * 64 + ((lane >> 4) << 4);
        int o0 = row0 * 256 + (colb ^ sw);
        int o1 = o0 + 16 * 256;
        bfrag8 ah0 = *(const bfrag8*)((const char*)Ahi + o0);
        bfrag8 al0 = *(const bfrag8*)((const char*)Alo + o0);
        bfrag8 ah1 = *(const bfrag8*)((const char*)Ahi + o1);
        bfrag8 al1 = *(const bfrag8*)((const char*)Alo + o1);
        const ushort* wbase = Wfg + kk * 1024 + lane * 8;
        #pragma unroll
        for (int t = 0; t < 8; ++t) {
            bfrag8 wh = *(const bfrag8*)(wbase + t * 4096);
            bfrag8 wl = *(const bfrag8*)(wbase + t * 4096 + 512);
            acc[0][t] = __builtin_amdgcn_mfma_f32_16x16x32_bf16(ah0, wh, acc[0][t], 0, 0, 0);
            acc[0][t] = __builtin_amdgcn_mfma_f32_16x16x32_bf16(ah0, wl, acc[0][t], 0, 0, 0);
            acc[0][t] = __builtin_amdgcn_mfma_f32_16x16x32_bf16(al0, wh, acc[0][t], 0, 0, 0);
            acc[0][t] = __builtin_amdgcn_mfma_f32_16x16x32_bf16(al0, wl, acc[0][t], 0, 0, 0);
            acc[1][t] = __builtin_amdgcn_mfma_f32_16x16x32_bf16(ah1, wh, acc[1][t], 0, 0, 0);
            acc[1][t] = __builtin_amdgcn_mfma_f32_16x16x32_bf16(ah1, wl, acc[1][t], 0, 0, 0);
            acc[1][t] = __builtin_amdgcn_mfma_f32_16x16x32_bf16(al1, wh, acc[1][t], 0, 0, 0);
            acc[1][t] = __builtin_amdgcn_mfma_f32_16x16x32_bf16(al1, wl, acc[1][t], 0, 0, 0);
        }
    }

    float* Eg = E + (size_t)g * (CATC * NCOND);
    const int colL = lane & 15;
    const int quad = lane >> 4;
    #pragma unroll
    for (int t = 0; t < 8; ++t) {
        int c = t * 16 + colL;
        #pragma unroll
        for (int gi = 0; gi < 2; ++gi) {
            int mbase = (2 * w + gi) * 16 + quad * 4;
            #pragma unroll
            for (int r = 0; r < 4; ++r) {
                int m = mbase + r;
                if (m < CATC) Eg[m * NCOND + c] = acc[gi][t][r];
            }
        }
    }
}

// ---------------------------------------------------------------------------
// transpose_wn: W_num/b_num (100x128 -> 128x100) for coalesced output-pass reads
// ---------------------------------------------------------------------------
__global__ __launch_bounds__(256)
void transpose_wn(const float* __restrict__ W_num, const float* __restrict__ b_num,
                  float* __restrict__ Wt, float* __restrict__ Bt)
{
    int idx = blockIdx.x * 256 + threadIdx.x;
    if (idx < NCOND * NNUM) {
        int c = idx / NNUM, j = idx - c * NNUM;
        Wt[idx] = W_num[j * NCOND + c];
        Bt[idx] = b_num[j * NCOND + c];
    }
}

// ---------------------------------------------------------------------------
// fused_out: per (sample, c-half). cat[g][c] = sigmoid(alpha*E + beta*Q + P)
// gathered from the 5.1 MB L2-hot E table -> LDS [g][c_loc] -> transposed,
// num branch fused, fully float4-coalesced output writes. No ws roundtrip.
// ---------------------------------------------------------------------------
__global__ __launch_bounds__(256)
void fused_out_kernel(const int* __restrict__ x_cat,
                      const float* __restrict__ x_num,
                      const float* __restrict__ Wt,   // [c][j]
                      const float* __restrict__ Bt,   // [c][j]
                      const float* __restrict__ Q,
                      const float* __restrict__ P,
                      const float2* __restrict__ S,
                      const float* __restrict__ E,
                      float* __restrict__ out)
{
    const int b   = blockIdx.x;
    const int h   = blockIdx.y;       // c-half: 0 or 1
    const int tid = threadIdx.x;
    __shared__ float T[NCAT * 65];    // [g][c_loc], pad 65
    __shared__ float xr[NNUM];
    __shared__ float al[NCAT], be[NCAT];
    __shared__ int   ei[NCAT];

    if (tid < NNUM) xr[tid] = x_num[b * NNUM + tid];
    if (tid < NCAT) {
        int idx = x_cat[(size_t)b * NCAT + tid];
        ei[tid] = idx;
        float2 s2 = S[tid * CATC + idx];
        al[tid] = s2.x;
        be[tid] = s2.y;
    }
    __syncthreads();

    const float4* E4 = (const float4*)E;
    const float4* Q4 = (const float4*)Q;
    const float4* P4 = (const float4*)P;
    #pragma unroll
    for (int it = 0; it < 7; ++it) {
        int i4 = it * 256 + tid;                  // 0..1599 float4s of this half
        if (i4 < NCAT * 16) {
            int g    = i4 >> 4;
            int c4   = i4 & 15;
            int col4 = h * 16 + c4;
            float4 e = E4[(size_t)(g * CATC + ei[g]) * 32 + col4];
            float4 q = Q4[g * 32 + col4];
            float4 p = P4[g * 32 + col4];
            float a = al[g], bb = be[g];
            float* d = &T[g * 65 + c4 * 4];
            d[0] = sigmoidf_(fmaf(a, e.x, fmaf(bb, q.x, p.x)));
            d[1] = sigmoidf_(fmaf(a, e.y, fmaf(bb, q.y, p.y)));
            d[2] = sigmoidf_(fmaf(a, e.z, fmaf(bb, q.z, p.z)));
            d[3] = sigmoidf_(fmaf(a, e.w, fmaf(bb, q.w, p.w)));
        }
    }
    __syncthreads();

    float4* outb = (float4*)(out + (size_t)b * (NCOND * 200)) + h * 3200;
    const float4* Wt4 = (const float4*)Wt;
    const float4* Bt4 = (const float4*)Bt;
    #pragma unroll
    for (int it = 0; it < 13; ++it) {
        int o4 = it * 256 + tid;                  // 0..3199 float4s of this half
        if (o4 < 64 * 50) {
            int c_loc = o4 / 50;
            int j4    = o4 - c_loc * 50;
            int c     = h * 64 + c_loc;
            float4 v;
            if (j4 < 25) {
                float4 wv = Wt4[c * 25 + j4];
                float4 bv = Bt4[c * 25 + j4];
                int j = j4 * 4;
                v.x = sigmoidf_(fmaf(xr[j],     wv.x, bv.x));
                v.y = sigmoidf_(fmaf(xr[j + 1], wv.y, bv.y));
                v.z = sigmoidf_(fmaf(xr[j + 2], wv.z, bv.z));
                v.w = sigmoidf_(fmaf(xr[j + 3], wv.w, bv.w));
            } else {
                int gg = (j4 - 25) * 4;
                v.x = T[(gg    ) * 65 + c_loc];
                v.y = T[(gg + 1) * 65 + c_loc];
                v.z = T[(gg + 2) * 65 + c_loc];
                v.w = T[(gg + 3) * 65 + c_loc];
            }
            outb[o4] = v;
        }
    }
}

extern "C" void kernel_launch(void* const* d_in, const int* in_sizes, int n_in,
                              void* d_out, int out_size, void* d_ws, size_t ws_size,
                              hipStream_t stream)
{
    const float* x_num  = (const float*)d_in[0];
    const int*   x_cat  = (const int*)  d_in[1];
    const float* W_num  = (const float*)d_in[2];
    const float* b_num  = (const float*)d_in[3];
    const float* emb    = (const float*)d_in[4];
    const float* gn_w   = (const float*)d_in[5];
    const float* gn_b   = (const float*)d_in[6];
    const float* W_cat  = (const float*)d_in[7];
    const float* b_cat  = (const float*)d_in[8];
    float* out = (float*)d_out;

    const int B = in_sizes[0] / NNUM;                 // 4096

    // ws layout (12 MB total; harness provides >=210 MB per prior rounds)
    float*  Wt = (float*)d_ws;                        // 12800
    float*  Bt = Wt + NCOND * NNUM;                   // 12800
    float*  Qb = Bt + NCOND * NNUM;                   // 12800
    float*  Pb = Qb + NCAT * NCOND;                   // 12800
    float2* Sb = (float2*)(Pb + NCAT * NCOND);        // 10000 float2
    float*  Eb = (float*)(Sb + NCAT * CATC);          // 1,280,000
    ushort* Wf = (ushort*)(Eb + NCAT * CATC * NCOND); // 3,276,800 ushort

    transpose_wn<<<(NCOND * NNUM + 255) / 256, 256, 0, stream>>>(W_num, b_num, Wt, Bt);
    prep_wcat<<<NCAT, 256, 0, stream>>>(W_cat, gn_w, Wf);
    prep_stats<<<(NCAT * CATC + 3) / 4, 256, 0, stream>>>(emb, Sb);
    prep_qp<<<NCAT, 128, 0, stream>>>(W_cat, gn_w, gn_b, b_cat, Qb, Pb);
    prep_E_kernel<<<NCAT, 256, 0, stream>>>(emb, Wf, Eb);
    fused_out_kernel<<<dim3(B, 2), 256, 0, stream>>>(x_cat, x_num, Wt, Bt, Qb, Pb, Sb, Eb, out);
}